// Round 12
// baseline (407.451 us; speedup 1.0000x reference)
//
#include <hip/hip_runtime.h>
#include <hip/hip_bf16.h>
#include <hip/hip_fp8.h>

typedef __attribute__((ext_vector_type(4))) float f32x4;
typedef __attribute__((ext_vector_type(4))) int   i32x4;
typedef __attribute__((ext_vector_type(8))) int   i32x8;

constexpr int BROWS = 4096;   // proteins (output rows)
constexpr int NCOLS = 8192;   // functions (output cols)
constexpr int DK    = 1024;   // inner dim
constexpr int BM = 256, BN = 256, BK = 128;   // K-tile = 128 fp8 elems (one MX MFMA K)
constexpr int NCB = NCOLS / BN;   // 32 column blocks
constexpr int NKT = DK / BK;      // 8 K-tiles
constexpr int NIT = NKT / 2;      // 4 iterations (2 K-tiles each)
constexpr int NWRDS = BROWS * NCOLS / 64;   // 512K 64-bit mask words

__device__ static inline void gload16(const void* g, void* l) {
  __builtin_amdgcn_global_load_lds(
      (const __attribute__((address_space(1))) void*)g,
      (__attribute__((address_space(3))) void*)l, 16, 0, 0);
}

// f32 -> fp8 e4m3 (OCP) conversion, 8 elems/thread; optional exp(-temp) fold.
__global__ void convert8_kernel(const float* __restrict__ src,
                                unsigned char* __restrict__ dst,
                                int n8, int applyScale,
                                const float* __restrict__ temp) {
  float scale = applyScale ? expf(-temp[0]) : 1.0f;
  int i = blockIdx.x * blockDim.x + threadIdx.x;
  if (i >= n8) return;
  const float4* s = reinterpret_cast<const float4*>(src) + (size_t)i * 2;
  float4 v0 = s[0], v1 = s[1];
  union { unsigned char b[8]; uint2 u; } o;
  o.b[0] = __hip_fp8_e4m3(v0.x * scale).__x;
  o.b[1] = __hip_fp8_e4m3(v0.y * scale).__x;
  o.b[2] = __hip_fp8_e4m3(v0.z * scale).__x;
  o.b[3] = __hip_fp8_e4m3(v0.w * scale).__x;
  o.b[4] = __hip_fp8_e4m3(v1.x * scale).__x;
  o.b[5] = __hip_fp8_e4m3(v1.y * scale).__x;
  o.b[6] = __hip_fp8_e4m3(v1.z * scale).__x;
  o.b[7] = __hip_fp8_e4m3(v1.w * scale).__x;
  reinterpret_cast<uint2*>(dst)[i] = o.u;
}

// Streaming mask compression at full BW: int4 (16B/lane) coalesced loads.
// Interleaved bitmask layout: for each 256-col group g, word g*4+k holds
// cols {4l+k} at bit l  (ballot bit l == lane l, lane reads cols 4l..4l+3).
__global__ void maskpack_kernel(const int* __restrict__ mask,
                                unsigned long long* __restrict__ bits) {
  const int lane = threadIdx.x & 63;
  const int gw   = (blockIdx.x * blockDim.x + threadIdx.x) >> 6;
  const int nw   = (gridDim.x * blockDim.x) >> 6;
  constexpr int NG = BROWS * NCOLS / 256;   // 131072 groups
  for (int base = gw * 8; base < NG; base += nw * 8) {
    int4 v[8];
#pragma unroll
    for (int j = 0; j < 8; ++j)
      v[j] = reinterpret_cast<const int4*>(mask)[(size_t)(base + j) * 64 + lane];
#pragma unroll
    for (int j = 0; j < 8; ++j) {
      unsigned long long b0 = __ballot(v[j].x == 1);
      unsigned long long b1 = __ballot(v[j].y == 1);
      unsigned long long b2 = __ballot(v[j].z == 1);
      unsigned long long b3 = __ballot(v[j].w == 1);
      if (lane == 0) {
        ulonglong4 o; o.x = b0; o.y = b1; o.z = b2; o.w = b3;
        reinterpret_cast<ulonglong4*>(bits)[base + j] = o;
      }
    }
  }
}

// stage one 128row x 128B fp8 half-tile (16 KB): linear LDS dest, T2 swizzle
// via pre-swizzled global source (rule #21; byte geometry identical to the
// bf16 version: 128 B per row, 0-conflict verified R4-R10).
__device__ __forceinline__ void stage_half(const unsigned char* __restrict__ g,
                                           unsigned char* l, int t, int kt) {
#pragma unroll
  for (int p = 0; p < 2; ++p) {
    const int off = p * 8192 + t * 16;        // byte offset within 16KB half buffer
    const int row = off >> 7;                 // 128 B per row (128 fp8)
    const int colSw = (off & 127) ^ ((row & 7) << 4);  // swizzled byte-in-row
    gload16(g + (size_t)row * DK + kt * 128 + colSw, l + off);
  }
}

// swizzled b128 read from fp8 LDS tile: 16 B at (row, l4*32 + h*16)
#define LDS_F4(base, row, h)                                                \
  (*reinterpret_cast<const i32x4*>(                                         \
      &(base)[(((row) * 128 + l4 * 32 + (h) * 16) ^ (((row) & 7) << 4))]))

__device__ __forceinline__ i32x8 cat8(i32x4 lo, i32x4 hi) {
  i32x8 r;
  r[0] = lo[0]; r[1] = lo[1]; r[2] = lo[2]; r[3] = lo[3];
  r[4] = hi[0]; r[5] = hi[1]; r[6] = hi[2]; r[7] = hi[3];
  return r;
}

// MX-scaled MFMA, scales fixed to 1.0 (E8M0 byte 127), fp8 e4m3 A and B.
#define MFMA_FP8(a, b, c) \
  __builtin_amdgcn_mfma_scale_f32_16x16x128_f8f6f4((a), (b), (c), 0, 0, 0, 127, 0, 127)

// A-frags (2 rowtiles x 32B) for quadrant q of this wave's 128-row stripe
#define READ_A(b, q)                                                          \
  aF[0] = cat8(LDS_F4(As[b][wm], (2*(q)    )*16 + l15, 0),                    \
               LDS_F4(As[b][wm], (2*(q)    )*16 + l15, 1));                   \
  aF[1] = cat8(LDS_F4(As[b][wm], (2*(q) + 1)*16 + l15, 0),                    \
               LDS_F4(As[b][wm], (2*(q) + 1)*16 + l15, 1));

#define READ_B(b)                                                             \
  bF[0] = cat8(LDS_F4(Bs[b][bhB], brB +  0 + l15, 0),                         \
               LDS_F4(Bs[b][bhB], brB +  0 + l15, 1));                        \
  bF[1] = cat8(LDS_F4(Bs[b][bhB], brB + 16 + l15, 0),                         \
               LDS_F4(Bs[b][bhB], brB + 16 + l15, 1));                        \
  bF[2] = cat8(LDS_F4(Bs[b][bhB], brB + 32 + l15, 0),                         \
               LDS_F4(Bs[b][bhB], brB + 32 + l15, 1));                        \
  bF[3] = cat8(LDS_F4(Bs[b][bhB], brB + 48 + l15, 0),                         \
               LDS_F4(Bs[b][bhB], brB + 48 + l15, 1));

#define COMPUTE(q)                                                            \
  __builtin_amdgcn_s_setprio(1);                                             \
  _Pragma("unroll") for (int mm = 0; mm < 2; ++mm)                            \
  _Pragma("unroll") for (int n = 0; n < 4; ++n) {                             \
    acc[2*(q)+mm][n] = MFMA_FP8(aF[mm], bF[n], acc[2*(q)+mm][n]);             \
  }                                                                           \
  __builtin_amdgcn_s_setprio(0);

#define PHASE_MID                                    \
  __builtin_amdgcn_s_barrier();                      \
  asm volatile("s_waitcnt lgkmcnt(0)" ::: "memory");

#define PHASE_END                                    \
  __builtin_amdgcn_s_barrier();

// 256x256 tile, 8 waves (2Mx4N), BK=128 fp8, 8-phase double-buffered schedule
// (R9 skeleton: counted vmcnt T4, setprio T5, swizzle T2).
// __launch_bounds__(512,1): LDS (144 KB) already limits to 1 block/CU, so the
// VGPR cap can be 256 -- the (512,2) cap at 128 caused R11's 520 MB spill.
// partials[row*NCB + cb] = {rowmax, sum exp(x-m), sum mask*x, count mask}
__global__ __launch_bounds__(512, 1)
void main_kernel(const unsigned char* __restrict__ Pb,
                 const unsigned char* __restrict__ Fb,
                 const unsigned long long* __restrict__ bits,
                 f32x4* __restrict__ partials) {
  __shared__ __align__(16) unsigned char As[2][2][128 * 128];  // [buf][half][swizzled]
  __shared__ __align__(16) unsigned char Bs[2][2][128 * 128];
  __shared__ float redM[4][256], redS[4][256], redP[4][256], redC[4][256];

  const int t    = threadIdx.x;
  const int lane = t & 63;
  const int w    = t >> 6;        // wave 0..7
  const int wm   = w >> 2;        // A half / output row half (0..1)
  const int wn   = w & 3;         // output col quarter (0..3)
  const int l15  = lane & 15;
  const int l4   = lane >> 4;
  const int bhB  = wn >> 1;       // which B half this wave reads
  const int brB  = (wn & 1) * 64; // base row within that B half

  const int brow = blockIdx.y * BM;
  const int bcol = blockIdx.x * BN;

  const unsigned char* Ag0 = Pb + (size_t)brow * DK;
  const unsigned char* Ag1 = Pb + (size_t)(brow + 128) * DK;
  const unsigned char* Bg0 = Fb + (size_t)bcol * DK;
  const unsigned char* Bg1 = Fb + (size_t)(bcol + 128) * DK;

  f32x4 acc[8][4] = {};
  i32x8 bF[4];
  i32x8 aF[2];

  // Prologue: stage B(0), A(0), B(1); drain so B(0)+A(0) landed, B(1) in flight.
  stage_half(Bg0, Bs[0][0], t, 0);
  stage_half(Bg1, Bs[0][1], t, 0);
  stage_half(Ag0, As[0][0], t, 0);
  stage_half(Ag1, As[0][1], t, 0);
  stage_half(Bg0, Bs[1][0], t, 1);
  stage_half(Bg1, Bs[1][1], t, 1);
  asm volatile("s_waitcnt vmcnt(4)" ::: "memory");
  __builtin_amdgcn_s_barrier();

  for (int i = 0; i < NIT; ++i) {
    const int t1 = 2 * i + 1;
    const bool more = (i < NIT - 1);
    // P1: tile t0 q0 (+ all B frags); stage A0(t1)
    READ_B(0); READ_A(0, 0);
    stage_half(Ag0, As[1][0], t, t1);
    PHASE_MID; COMPUTE(0); PHASE_END;
    // P2: q1; stage A1(t1)
    READ_A(0, 1);
    stage_half(Ag1, As[1][1], t, t1);
    PHASE_MID; COMPUTE(1); PHASE_END;
    // P3: q2; stage B0(t0+2)
    READ_A(0, 2);
    if (more) stage_half(Bg0, Bs[0][0], t, t1 + 1);
    PHASE_MID; COMPUTE(2); PHASE_END;
    // P4: q3; stage B1(t0+2); K-tile drain (counted; 0 on last iter)
    READ_A(0, 3);
    if (more) stage_half(Bg1, Bs[0][1], t, t1 + 1);
    PHASE_MID; COMPUTE(3);
    if (more) { asm volatile("s_waitcnt vmcnt(4)" ::: "memory"); }
    else      { asm volatile("s_waitcnt vmcnt(0)" ::: "memory"); }
    PHASE_END;
    // P5: tile t1 q0 (+ all B frags); stage A0(t0+2)
    READ_B(1); READ_A(1, 0);
    if (more) stage_half(Ag0, As[0][0], t, t1 + 1);
    PHASE_MID; COMPUTE(0); PHASE_END;
    // P6: q1; stage A1(t0+2)
    READ_A(1, 1);
    if (more) stage_half(Ag1, As[0][1], t, t1 + 1);
    PHASE_MID; COMPUTE(1); PHASE_END;
    // P7: q2; stage B0(t1+2)
    READ_A(1, 2);
    if (more) stage_half(Bg0, Bs[1][0], t, t1 + 2);
    PHASE_MID; COMPUTE(2); PHASE_END;
    // P8: q3; stage B1(t1+2); K-tile drain
    READ_A(1, 3);
    if (more) stage_half(Bg1, Bs[1][1], t, t1 + 2);
    PHASE_MID; COMPUTE(3);
    if (more) { asm volatile("s_waitcnt vmcnt(4)" ::: "memory"); }
    PHASE_END;
  }

  // Epilogue: C/D layout col=lane&15, row=(lane>>4)*4+reg (shape-determined,
  // dtype-independent: m121-m128 verified for f8f6f4-scaled too).
  // Interleaved bitmask: col c of 256-chunk -> word c&3, bit c>>2.
#pragma unroll
  for (int m = 0; m < 8; ++m) {
#pragma unroll
    for (int r = 0; r < 4; ++r) {
      float v0 = acc[m][0][r], v1 = acc[m][1][r], v2 = acc[m][2][r], v3 = acc[m][3][r];
      float mx = fmaxf(fmaxf(v0, v1), fmaxf(v2, v3));
#pragma unroll
      for (int s = 1; s < 16; s <<= 1) mx = fmaxf(mx, __shfl_xor(mx, s, 64));
      float se = __expf(v0 - mx) + __expf(v1 - mx) + __expf(v2 - mx) + __expf(v3 - mx);

      const int lr = wm * 128 + m * 16 + l4 * 4 + r;
      const unsigned long long wB =
          bits[(size_t)(brow + lr) * (NCOLS / 64) + (size_t)blockIdx.x * 4 + (l15 & 3)];
      const int bsh = wn * 16 + (l15 >> 2);
      float ps = 0.f, pc = 0.f;
      if ((wB >> (bsh     )) & 1ull) { ps += v0; pc += 1.f; }
      if ((wB >> (bsh +  4)) & 1ull) { ps += v1; pc += 1.f; }
      if ((wB >> (bsh +  8)) & 1ull) { ps += v2; pc += 1.f; }
      if ((wB >> (bsh + 12)) & 1ull) { ps += v3; pc += 1.f; }
#pragma unroll
      for (int s = 1; s < 16; s <<= 1) {
        se += __shfl_xor(se, s, 64);
        ps += __shfl_xor(ps, s, 64);
        pc += __shfl_xor(pc, s, 64);
      }
      if (l15 == 0) {
        redM[wn][lr] = mx;
        redS[wn][lr] = se;
        redP[wn][lr] = ps;
        redC[wn][lr] = pc;
      }
    }
  }
  __syncthreads();

  if (t < 256) {
    float m0 = redM[0][t], m1 = redM[1][t], m2 = redM[2][t], m3 = redM[3][t];
    float m  = fmaxf(fmaxf(m0, m1), fmaxf(m2, m3));
    float s  = redS[0][t] * __expf(m0 - m) + redS[1][t] * __expf(m1 - m)
             + redS[2][t] * __expf(m2 - m) + redS[3][t] * __expf(m3 - m);
    float ps = redP[0][t] + redP[1][t] + redP[2][t] + redP[3][t];
    float pc = redC[0][t] + redC[1][t] + redC[2][t] + redC[3][t];
    f32x4 out4;
    out4.x = m; out4.y = s; out4.z = ps; out4.w = pc;
    partials[(size_t)(brow + t) * NCB + blockIdx.x] = out4;
  }
}

// One wave per row: combine the 32 column-block partials -> per-row contribution.
__global__ void row_reduce_kernel(const f32x4* __restrict__ partials,
                                  float* __restrict__ rowContrib,
                                  float* __restrict__ rowCnt) {
  const int row  = blockIdx.x * 4 + (threadIdx.x >> 6);
  const int lane = threadIdx.x & 63;
  f32x4 p = partials[(size_t)row * NCB + (lane & 31)];
  float m = p.x;
#pragma unroll
  for (int s = 1; s < 32; s <<= 1) m = fmaxf(m, __shfl_xor(m, s, 64));
  float se = p.y * __expf(p.x - m);
  float ps = p.z, pc = p.w;
#pragma unroll
  for (int s = 1; s < 32; s <<= 1) {
    se += __shfl_xor(se, s, 64);
    ps += __shfl_xor(ps, s, 64);
    pc += __shfl_xor(pc, s, 64);
  }
  if (lane == 0) {
    float lse = m + logf(se);
    rowContrib[row] = pc * lse - ps;
    rowCnt[row]     = pc;
  }
}

__global__ void final_kernel(const float* __restrict__ rowContrib,
                             const float* __restrict__ rowCnt,
                             float* __restrict__ out) {
  __shared__ double sC[256];
  __shared__ double sN[256];
  double c = 0.0, n = 0.0;
  for (int i = threadIdx.x; i < BROWS; i += 256) {
    c += (double)rowContrib[i];
    n += (double)rowCnt[i];
  }
  sC[threadIdx.x] = c;
  sN[threadIdx.x] = n;
  __syncthreads();
  for (int s = 128; s > 0; s >>= 1) {
    if ((int)threadIdx.x < s) {
      sC[threadIdx.x] += sC[threadIdx.x + s];
      sN[threadIdx.x] += sN[threadIdx.x + s];
    }
    __syncthreads();
  }
  if (threadIdx.x == 0) out[0] = (sN[0] > 0.0) ? (float)(sC[0] / sN[0]) : 0.0f;
}

extern "C" void kernel_launch(void* const* d_in, const int* in_sizes, int n_in,
                              void* d_out, int out_size, void* d_ws, size_t ws_size,
                              hipStream_t stream) {
  const float* P    = (const float*)d_in[0];
  const float* F    = (const float*)d_in[1];
  const int*   mask = (const int*)d_in[2];
  const float* temp = (const float*)d_in[3];
  float* out = (float*)d_out;

  char* ws = (char*)d_ws;
  unsigned char* Pb8 = (unsigned char*)ws;                                    // 4 MB
  unsigned char* Fb8 = (unsigned char*)(ws + (size_t)BROWS * DK);             // 8 MB
  unsigned long long* bits = (unsigned long long*)(ws + (size_t)(BROWS + NCOLS) * DK);  // 4 MB
  f32x4* partials    = (f32x4*)((char*)bits + (size_t)NWRDS * 8);             // 2 MB
  float* rowContrib  = (float*)((char*)partials + (size_t)BROWS * NCB * sizeof(f32x4));
  float* rowCnt      = rowContrib + BROWS;

  const int nP8 = BROWS * DK / 8;
  const int nF8 = NCOLS * DK / 8;
  hipLaunchKernelGGL(convert8_kernel, dim3(nP8 / 256), dim3(256), 0, stream, P, Pb8, nP8, 1, temp);
  hipLaunchKernelGGL(convert8_kernel, dim3(nF8 / 256), dim3(256), 0, stream, F, Fb8, nF8, 0, temp);
  hipLaunchKernelGGL(maskpack_kernel, dim3(2048), dim3(256), 0, stream, mask, bits);
  hipLaunchKernelGGL(main_kernel, dim3(NCOLS / BN, BROWS / BM), dim3(512), 0, stream, Pb8, Fb8, bits, partials);
  hipLaunchKernelGGL(row_reduce_kernel, dim3(BROWS / 4), dim3(256), 0, stream, partials, rowContrib, rowCnt);
  hipLaunchKernelGGL(final_kernel, dim3(1), dim3(256), 0, stream, rowContrib, rowCnt, out);
}

// Round 13
// 115.283 us; speedup vs baseline: 3.5344x; 3.5344x over previous
//
#include <hip/hip_runtime.h>
#include <hip/hip_bf16.h>

typedef __attribute__((ext_vector_type(4))) float f32x4;
typedef __attribute__((ext_vector_type(8))) __bf16 bf16x8;
typedef __attribute__((ext_vector_type(8))) unsigned short u16x8;

constexpr int BROWS = 4096;   // proteins (output rows)
constexpr int NCOLS = 8192;   // functions (output cols)
constexpr int DK    = 1024;   // inner dim
constexpr int BM = 256, BN = 256, BK = 64;
constexpr int NCB = NCOLS / BN;   // 32 column blocks
constexpr int NKT = DK / BK;      // 16 K-tiles
constexpr int NIT = NKT / 2;      // 8 iterations (2 K-tiles each)

__device__ static inline unsigned short f2bf(float f) {
  unsigned int u = __builtin_bit_cast(unsigned int, f);
  u += 0x7FFFu + ((u >> 16) & 1u);
  return (unsigned short)(u >> 16);
}

__device__ static inline void gload16(const void* g, void* l) {
  __builtin_amdgcn_global_load_lds(
      (const __attribute__((address_space(1))) void*)g,
      (__attribute__((address_space(3))) void*)l, 16, 0, 0);
}

__global__ void convert_kernel(const float* __restrict__ src,
                               unsigned short* __restrict__ dst,
                               int n4, int applyScale,
                               const float* __restrict__ temp) {
  float scale = applyScale ? expf(-temp[0]) : 1.0f;
  int i = blockIdx.x * blockDim.x + threadIdx.x;
  if (i >= n4) return;
  float4 v = reinterpret_cast<const float4*>(src)[i];
  ushort4 o;
  o.x = f2bf(v.x * scale);
  o.y = f2bf(v.y * scale);
  o.z = f2bf(v.z * scale);
  o.w = f2bf(v.w * scale);
  reinterpret_cast<ushort4*>(dst)[i] = o;
}

// stage one 128x64-bf16 half-tile (16 KB): linear LDS dest, T2 swizzle via
// pre-swizzled global source (rule #21; verified 0-conflict R4-R10).
__device__ __forceinline__ void stage_half(const unsigned short* __restrict__ g,
                                           unsigned short* l, int t, int kt) {
#pragma unroll
  for (int p = 0; p < 2; ++p) {
    const int off = p * 8192 + t * 16;        // byte offset within 16KB half buffer
    const int row = off >> 7;                 // 128 B per row (64 bf16)
    const int keSw = ((off & 127) >> 1) ^ ((row & 7) << 3);  // swizzled elem-in-row
    gload16(g + (size_t)row * DK + kt * 64 + keSw, l + (off >> 1));
  }
}

#define MFMA_BF16 __builtin_amdgcn_mfma_f32_16x16x32_bf16

// swizzled read: element index ^ ((row&7)<<3)  <=>  byte ^ ((row&7)<<4)
#define LDS_FRAG(base, row, kk)                                             \
  __builtin_bit_cast(bf16x8, *reinterpret_cast<const u16x8*>(               \
      &(base)[((row) * 64 + (kk) * 32 + l4 * 8) ^ (((row) & 7) << 3)]))

#define READ_A(b, q)                                              \
  aFr[0][0] = LDS_FRAG(As[b][wm], (2*(q)    )*16 + l15, 0);       \
  aFr[0][1] = LDS_FRAG(As[b][wm], (2*(q)    )*16 + l15, 1);       \
  aFr[1][0] = LDS_FRAG(As[b][wm], (2*(q) + 1)*16 + l15, 0);       \
  aFr[1][1] = LDS_FRAG(As[b][wm], (2*(q) + 1)*16 + l15, 1);

#define READ_B(b)                                                 \
  bFr[0][0] = LDS_FRAG(Bs[b][bhB], brB +  0 + l15, 0);            \
  bFr[0][1] = LDS_FRAG(Bs[b][bhB], brB +  0 + l15, 1);            \
  bFr[1][0] = LDS_FRAG(Bs[b][bhB], brB + 16 + l15, 0);            \
  bFr[1][1] = LDS_FRAG(Bs[b][bhB], brB + 16 + l15, 1);            \
  bFr[2][0] = LDS_FRAG(Bs[b][bhB], brB + 32 + l15, 0);            \
  bFr[2][1] = LDS_FRAG(Bs[b][bhB], brB + 32 + l15, 1);            \
  bFr[3][0] = LDS_FRAG(Bs[b][bhB], brB + 48 + l15, 0);            \
  bFr[3][1] = LDS_FRAG(Bs[b][bhB], brB + 48 + l15, 1);

#define COMPUTE(q)                                                                  \
  __builtin_amdgcn_s_setprio(1);                                                   \
  _Pragma("unroll") for (int mm = 0; mm < 2; ++mm)                                  \
  _Pragma("unroll") for (int n = 0; n < 4; ++n) {                                   \
    acc[2*(q)+mm][n] = MFMA_BF16(aFr[mm][0], bFr[n][0], acc[2*(q)+mm][n], 0, 0, 0); \
    acc[2*(q)+mm][n] = MFMA_BF16(aFr[mm][1], bFr[n][1], acc[2*(q)+mm][n], 0, 0, 0); \
  }                                                                                 \
  __builtin_amdgcn_s_setprio(0);

// ONE barrier per phase (the MID barrier + forced lgkmcnt(0) are removed --
// R10's validated model showed they serialize the LDS and MFMA epochs).
// Within-wave read->MFMA ordering: compiler's counted lgkmcnt (automatic).
// Cross-wave stage->read publication: vmcnt drain BEFORE this barrier at
// P4/P8 (ledger re-audited for 1-phase wave drift; all hazard windows are
// closed by an earlier phase-end barrier). Compiler fences stop hoisting
// of next-phase ds_reads across the raw s_barrier.
#define PHASE_BAR                          \
  asm volatile("" ::: "memory");           \
  __builtin_amdgcn_s_barrier();            \
  asm volatile("" ::: "memory");

// 256x256 tile, 8 waves (2Mx4N), BK=64, 8-phase double-buffered, counted
// vmcnt (T4) + setprio (T5) + swizzle (T2), single-barrier phases.
// Mask is read int32 directly in the epilogue (R4 form -- best wall-clock).
// partials[row*NCB + cb] = {rowmax, sum exp(x-m), sum mask*x, count mask}
__global__ __launch_bounds__(512, 2)
void main_kernel(const unsigned short* __restrict__ Pb,
                 const unsigned short* __restrict__ Fb,
                 const int* __restrict__ mask,
                 f32x4* __restrict__ partials) {
  __shared__ __align__(16) unsigned short As[2][2][128 * 64];  // [buf][half][swizzled]
  __shared__ __align__(16) unsigned short Bs[2][2][128 * 64];
  __shared__ float redM[4][256], redS[4][256], redP[4][256], redC[4][256];

  const int t    = threadIdx.x;
  const int lane = t & 63;
  const int w    = t >> 6;        // wave 0..7
  const int wm   = w >> 2;        // A half / output row half (0..1)
  const int wn   = w & 3;         // output col quarter (0..3)
  const int l15  = lane & 15;
  const int l4   = lane >> 4;
  const int bhB  = wn >> 1;       // which B half this wave reads
  const int brB  = (wn & 1) * 64; // base row within that B half

  const int brow = blockIdx.y * BM;
  const int bcol = blockIdx.x * BN;

  const unsigned short* Ag0 = Pb + (size_t)brow * DK;
  const unsigned short* Ag1 = Pb + (size_t)(brow + 128) * DK;
  const unsigned short* Bg0 = Fb + (size_t)bcol * DK;
  const unsigned short* Bg1 = Fb + (size_t)(bcol + 128) * DK;

  f32x4 acc[8][4] = {};
  bf16x8 bFr[4][2];
  bf16x8 aFr[2][2];

  // Prologue: stage B(0), A(0), B(1); drain so B(0)+A(0) landed, B(1) in flight.
  stage_half(Bg0, Bs[0][0], t, 0);
  stage_half(Bg1, Bs[0][1], t, 0);
  stage_half(Ag0, As[0][0], t, 0);
  stage_half(Ag1, As[0][1], t, 0);
  stage_half(Bg0, Bs[1][0], t, 1);
  stage_half(Bg1, Bs[1][1], t, 1);
  asm volatile("s_waitcnt vmcnt(4)" ::: "memory");
  PHASE_BAR;

  for (int i = 0; i < NIT; ++i) {
    const int t1 = 2 * i + 1;
    const bool more = (i < NIT - 1);
    // P1: tile t0 q0 (+ all B frags); stage A0(t1)
    READ_B(0); READ_A(0, 0);
    stage_half(Ag0, As[1][0], t, t1);
    COMPUTE(0); PHASE_BAR;
    // P2: q1; stage A1(t1)
    READ_A(0, 1);
    stage_half(Ag1, As[1][1], t, t1);
    COMPUTE(1); PHASE_BAR;
    // P3: q2; stage B0(t0+2)
    READ_A(0, 2);
    if (more) stage_half(Bg0, Bs[0][0], t, t1 + 1);
    COMPUTE(2); PHASE_BAR;
    // P4: q3; stage B1(t0+2); K-tile drain (counted; 0 on last iter)
    READ_A(0, 3);
    if (more) stage_half(Bg1, Bs[0][1], t, t1 + 1);
    COMPUTE(3);
    if (more) { asm volatile("s_waitcnt vmcnt(4)" ::: "memory"); }
    else      { asm volatile("s_waitcnt vmcnt(0)" ::: "memory"); }
    PHASE_BAR;
    // P5: tile t1 q0 (+ all B frags); stage A0(t0+2)
    READ_B(1); READ_A(1, 0);
    if (more) stage_half(Ag0, As[0][0], t, t1 + 1);
    COMPUTE(0); PHASE_BAR;
    // P6: q1; stage A1(t0+2)
    READ_A(1, 1);
    if (more) stage_half(Ag1, As[0][1], t, t1 + 1);
    COMPUTE(1); PHASE_BAR;
    // P7: q2; stage B0(t1+2)
    READ_A(1, 2);
    if (more) stage_half(Bg0, Bs[1][0], t, t1 + 2);
    COMPUTE(2); PHASE_BAR;
    // P8: q3; stage B1(t1+2); K-tile drain
    READ_A(1, 3);
    if (more) stage_half(Bg1, Bs[1][1], t, t1 + 2);
    COMPUTE(3);
    if (more) { asm volatile("s_waitcnt vmcnt(4)" ::: "memory"); }
    PHASE_BAR;
  }

  // Epilogue: C/D layout col=lane&15, row=(lane>>4)*4+reg (m89-verified).
#pragma unroll
  for (int m = 0; m < 8; ++m) {
#pragma unroll
    for (int r = 0; r < 4; ++r) {
      float v0 = acc[m][0][r], v1 = acc[m][1][r], v2 = acc[m][2][r], v3 = acc[m][3][r];
      float mx = fmaxf(fmaxf(v0, v1), fmaxf(v2, v3));
#pragma unroll
      for (int s = 1; s < 16; s <<= 1) mx = fmaxf(mx, __shfl_xor(mx, s, 64));
      float se = __expf(v0 - mx) + __expf(v1 - mx) + __expf(v2 - mx) + __expf(v3 - mx);

      const int lr = wm * 128 + m * 16 + l4 * 4 + r;
      const int* mrow = mask + (size_t)(brow + lr) * NCOLS + bcol + wn * 64 + l15;
      float ps = 0.f, pc = 0.f;
      if (mrow[0]  == 1) { ps += v0; pc += 1.f; }
      if (mrow[16] == 1) { ps += v1; pc += 1.f; }
      if (mrow[32] == 1) { ps += v2; pc += 1.f; }
      if (mrow[48] == 1) { ps += v3; pc += 1.f; }
#pragma unroll
      for (int s = 1; s < 16; s <<= 1) {
        se += __shfl_xor(se, s, 64);
        ps += __shfl_xor(ps, s, 64);
        pc += __shfl_xor(pc, s, 64);
      }
      if (l15 == 0) {
        redM[wn][lr] = mx;
        redS[wn][lr] = se;
        redP[wn][lr] = ps;
        redC[wn][lr] = pc;
      }
    }
  }
  __syncthreads();

  if (t < 256) {
    float m0 = redM[0][t], m1 = redM[1][t], m2 = redM[2][t], m3 = redM[3][t];
    float m  = fmaxf(fmaxf(m0, m1), fmaxf(m2, m3));
    float s  = redS[0][t] * __expf(m0 - m) + redS[1][t] * __expf(m1 - m)
             + redS[2][t] * __expf(m2 - m) + redS[3][t] * __expf(m3 - m);
    float ps = redP[0][t] + redP[1][t] + redP[2][t] + redP[3][t];
    float pc = redC[0][t] + redC[1][t] + redC[2][t] + redC[3][t];
    f32x4 out4;
    out4.x = m; out4.y = s; out4.z = ps; out4.w = pc;
    partials[(size_t)(brow + t) * NCB + blockIdx.x] = out4;
  }
}

// One wave per row: combine the 32 column-block partials -> per-row contribution.
__global__ void row_reduce_kernel(const f32x4* __restrict__ partials,
                                  float* __restrict__ rowContrib,
                                  float* __restrict__ rowCnt) {
  const int row  = blockIdx.x * 4 + (threadIdx.x >> 6);
  const int lane = threadIdx.x & 63;
  f32x4 p = partials[(size_t)row * NCB + (lane & 31)];
  float m = p.x;
#pragma unroll
  for (int s = 1; s < 32; s <<= 1) m = fmaxf(m, __shfl_xor(m, s, 64));
  float se = p.y * __expf(p.x - m);
  float ps = p.z, pc = p.w;
#pragma unroll
  for (int s = 1; s < 32; s <<= 1) {
    se += __shfl_xor(se, s, 64);
    ps += __shfl_xor(ps, s, 64);
    pc += __shfl_xor(pc, s, 64);
  }
  if (lane == 0) {
    float lse = m + logf(se);
    rowContrib[row] = pc * lse - ps;
    rowCnt[row]     = pc;
  }
}

__global__ void final_kernel(const float* __restrict__ rowContrib,
                             const float* __restrict__ rowCnt,
                             float* __restrict__ out) {
  __shared__ double sC[256];
  __shared__ double sN[256];
  double c = 0.0, n = 0.0;
  for (int i = threadIdx.x; i < BROWS; i += 256) {
    c += (double)rowContrib[i];
    n += (double)rowCnt[i];
  }
  sC[threadIdx.x] = c;
  sN[threadIdx.x] = n;
  __syncthreads();
  for (int s = 128; s > 0; s >>= 1) {
    if ((int)threadIdx.x < s) {
      sC[threadIdx.x] += sC[threadIdx.x + s];
      sN[threadIdx.x] += sN[threadIdx.x + s];
    }
    __syncthreads();
  }
  if (threadIdx.x == 0) out[0] = (sN[0] > 0.0) ? (float)(sC[0] / sN[0]) : 0.0f;
}

extern "C" void kernel_launch(void* const* d_in, const int* in_sizes, int n_in,
                              void* d_out, int out_size, void* d_ws, size_t ws_size,
                              hipStream_t stream) {
  const float* P    = (const float*)d_in[0];
  const float* F    = (const float*)d_in[1];
  const int*   mask = (const int*)d_in[2];
  const float* temp = (const float*)d_in[3];
  float* out = (float*)d_out;

  char* ws = (char*)d_ws;
  unsigned short* Pb = (unsigned short*)ws;                              // 8 MB
  unsigned short* Fb = (unsigned short*)(ws + (size_t)BROWS * DK * 2);   // 16 MB
  f32x4* partials    = (f32x4*)(ws + (size_t)(BROWS + NCOLS) * DK * 2);  // 2 MB
  float* rowContrib  = (float*)((char*)partials + (size_t)BROWS * NCB * sizeof(f32x4));
  float* rowCnt      = rowContrib + BROWS;

  const int nP4 = BROWS * DK / 4;
  const int nF4 = NCOLS * DK / 4;
  hipLaunchKernelGGL(convert_kernel, dim3(nP4 / 256), dim3(256), 0, stream, P, Pb, nP4, 1, temp);
  hipLaunchKernelGGL(convert_kernel, dim3(nF4 / 256), dim3(256), 0, stream, F, Fb, nF4, 0, temp);
  hipLaunchKernelGGL(main_kernel, dim3(NCOLS / BN, BROWS / BM), dim3(512), 0, stream, Pb, Fb, mask, partials);
  hipLaunchKernelGGL(row_reduce_kernel, dim3(BROWS / 4), dim3(256), 0, stream, partials, rowContrib, rowCnt);
  hipLaunchKernelGGL(final_kernel, dim3(1), dim3(256), 0, stream, rowContrib, rowCnt, out);
}